// Round 6
// baseline (571.598 us; speedup 1.0000x reference)
//
#include <hip/hip_runtime.h>
#include <stdint.h>

#define HDIM 64
#define TDIM 512

// One wave per batch. Entire recurrence in ONE inline-asm block with fixed
// registers — rounds 2-4 proved the compiler will not keep W_hh resident
// (VGPR_Count stuck at 48-52; ~451 VALU cyc/step vs ~270 floor).
// Round-5 asm NaN'd: suspected SW-managed hazard violations (SALU->lane-select
// distance 1-2; trans-op result consumed next instr). This version hardens:
//   - s_add s13 hoisted ~75 instr before its lane-select use
//   - s_nop 4 after entry s_mov s13,0
//   - s_nop 1 after v_exp / v_rcp before dependent reads
// Register map:
//   v40-v103 : W_hh row `lane` (64 f32, loaded once, clobber-pinned)
//   v104-107 : 4 fma accumulators; v111 : h;  v112-115 : temps/addr
//   v116-123 : x chunks (8 x 64 steps, lane j = x[c*64+j])
//   s15      : xt broadcast; s16-s79 : h[0..63] broadcast (batched readlane,
//              >=60-instr write->read distance)

// ---- asm text builders ----
#define RL(s, l) "v_readlane_b32 s" #s ", v111, " #l "\n\t"

#define RL_ALL \
  RL(16,0)  RL(17,1)  RL(18,2)  RL(19,3)  RL(20,4)  RL(21,5)  RL(22,6)  RL(23,7)  \
  RL(24,8)  RL(25,9)  RL(26,10) RL(27,11) RL(28,12) RL(29,13) RL(30,14) RL(31,15) \
  RL(32,16) RL(33,17) RL(34,18) RL(35,19) RL(36,20) RL(37,21) RL(38,22) RL(39,23) \
  RL(40,24) RL(41,25) RL(42,26) RL(43,27) RL(44,28) RL(45,29) RL(46,30) RL(47,31) \
  RL(48,32) RL(49,33) RL(50,34) RL(51,35) RL(52,36) RL(53,37) RL(54,38) RL(55,39) \
  RL(56,40) RL(57,41) RL(58,42) RL(59,43) RL(60,44) RL(61,45) RL(62,46) RL(63,47) \
  RL(64,48) RL(65,49) RL(66,50) RL(67,51) RL(68,52) RL(69,53) RL(70,54) RL(71,55) \
  RL(72,56) RL(73,57) RL(74,58) RL(75,59) RL(76,60) RL(77,61) RL(78,62) RL(79,63)

#define FM(a, s, w) "v_fmac_f32 v" #a ", s" #s ", v" #w "\n\t"

#define FM_ALL \
  "v_fma_f32 v104, s15, %[wih], %[bias]\n\t"                       \
  "v_mul_f32 v105, s17, v41\n\t"                                   \
  "v_mul_f32 v106, s18, v42\n\t"                                   \
  "v_mul_f32 v107, s19, v43\n\t"                                   \
  FM(104,16,40)                                                    \
  FM(104,20,44) FM(105,21,45) FM(106,22,46) FM(107,23,47)          \
  FM(104,24,48) FM(105,25,49) FM(106,26,50) FM(107,27,51)          \
  FM(104,28,52) FM(105,29,53) FM(106,30,54) FM(107,31,55)          \
  FM(104,32,56) FM(105,33,57) FM(106,34,58) FM(107,35,59)          \
  FM(104,36,60) FM(105,37,61) FM(106,38,62) FM(107,39,63)          \
  FM(104,40,64) FM(105,41,65) FM(106,42,66) FM(107,43,67)          \
  FM(104,44,68) FM(105,45,69) FM(106,46,70) FM(107,47,71)          \
  FM(104,48,72) FM(105,49,73) FM(106,50,74) FM(107,51,75)          \
  FM(104,52,76) FM(105,53,77) FM(106,54,78) FM(107,55,79)          \
  FM(104,56,80) FM(105,57,81) FM(106,58,82) FM(107,59,83)          \
  FM(104,60,84) FM(105,61,85) FM(106,62,86) FM(107,63,87)          \
  FM(104,64,88) FM(105,65,89) FM(106,66,90) FM(107,67,91)          \
  FM(104,68,92) FM(105,69,93) FM(106,70,94) FM(107,71,95)          \
  FM(104,72,96) FM(105,73,97) FM(106,74,98) FM(107,75,99)          \
  FM(104,76,100) FM(105,77,101) FM(106,78,102) FM(107,79,103)

// tanh with trans-op hazard padding
#define TANH_H \
  "v_add_f32 v104, v104, v105\n\t"            \
  "v_add_f32 v106, v106, v107\n\t"            \
  "v_add_f32 v104, v104, v106\n\t"            \
  "v_mul_f32 v105, 0x4038aa3b, v104\n\t"      \
  "v_exp_f32 v105, v105\n\t"                  \
  "s_nop 1\n\t"                               \
  "v_add_f32 v105, 1.0, v105\n\t"             \
  "v_rcp_f32 v105, v105\n\t"                  \
  "s_nop 1\n\t"                               \
  "v_fma_f32 v111, -2.0, v105, 1.0\n\t"

// one 64-timestep chunk; s13 incremented ~75 instr before its lane-select use
#define CHUNK(c, xreg) \
  "s_mov_b32 s13, 0\n\t"                      \
  "s_nop 4\n\t"                               \
  "Lc" #c "_%=:\n\t"                          \
  "v_readlane_b32 s15, " xreg ", s13\n\t"     \
  RL_ALL                                      \
  "s_add_u32 s13, s13, 1\n\t"                 \
  FM_ALL                                      \
  TANH_H                                      \
  "s_cmp_lt_u32 s13, 64\n\t"                  \
  "s_cbranch_scc1 Lc" #c "_%=\n\t"

__global__ __launch_bounds__(256, 2)
void rnn_asm_f32(const float* __restrict__ x,
                 const float* __restrict__ W_ih,
                 const float* __restrict__ W_hh,
                 const float* __restrict__ b_ih,
                 const float* __restrict__ b_hh,
                 const float* __restrict__ fc_w,
                 const float* __restrict__ fc_b,
                 float* __restrict__ out,
                 int B)
{
    const int lane  = threadIdx.x & 63;
    const int batch = blockIdx.x * (blockDim.x >> 6) + (threadIdx.x >> 6);
    if (batch >= B) return;   // wave-uniform (B divides grid exactly)

    const float w_ih_l = W_ih[lane];
    const float bias_l = b_ih[lane] + b_hh[lane];

    const uintptr_t xp = (uintptr_t)(x + (size_t)batch * TDIM + lane);
    const uintptr_t wp = (uintptr_t)(W_hh + (size_t)lane * HDIM);
    const uint32_t xlo = (uint32_t)xp, xhi = (uint32_t)(xp >> 32);
    const uint32_t wlo = (uint32_t)wp, whi = (uint32_t)(wp >> 32);

    float h;
    asm volatile(
        // ---- x: 8 chunks of 64 timesteps, lane j holds x[c*64+j] ----
        "v_mov_b32 v112, %[xlo]\n\t"
        "v_mov_b32 v113, %[xhi]\n\t"
        "global_load_dword v116, v[112:113], off\n\t"
        "global_load_dword v117, v[112:113], off offset:256\n\t"
        "global_load_dword v118, v[112:113], off offset:512\n\t"
        "global_load_dword v119, v[112:113], off offset:768\n\t"
        "global_load_dword v120, v[112:113], off offset:1024\n\t"
        "global_load_dword v121, v[112:113], off offset:1280\n\t"
        "global_load_dword v122, v[112:113], off offset:1536\n\t"
        "global_load_dword v123, v[112:113], off offset:1792\n\t"
        // ---- W_hh row -> v40..v103 (resident forever) ----
        "v_mov_b32 v112, %[wlo]\n\t"
        "v_mov_b32 v113, %[whi]\n\t"
        "global_load_dwordx4 v[40:43],   v[112:113], off\n\t"
        "global_load_dwordx4 v[44:47],   v[112:113], off offset:16\n\t"
        "global_load_dwordx4 v[48:51],   v[112:113], off offset:32\n\t"
        "global_load_dwordx4 v[52:55],   v[112:113], off offset:48\n\t"
        "global_load_dwordx4 v[56:59],   v[112:113], off offset:64\n\t"
        "global_load_dwordx4 v[60:63],   v[112:113], off offset:80\n\t"
        "global_load_dwordx4 v[64:67],   v[112:113], off offset:96\n\t"
        "global_load_dwordx4 v[68:71],   v[112:113], off offset:112\n\t"
        "global_load_dwordx4 v[72:75],   v[112:113], off offset:128\n\t"
        "global_load_dwordx4 v[76:79],   v[112:113], off offset:144\n\t"
        "global_load_dwordx4 v[80:83],   v[112:113], off offset:160\n\t"
        "global_load_dwordx4 v[84:87],   v[112:113], off offset:176\n\t"
        "global_load_dwordx4 v[88:91],   v[112:113], off offset:192\n\t"
        "global_load_dwordx4 v[92:95],   v[112:113], off offset:208\n\t"
        "global_load_dwordx4 v[96:99],   v[112:113], off offset:224\n\t"
        "global_load_dwordx4 v[100:103], v[112:113], off offset:240\n\t"
        "v_mov_b32 v111, 0\n\t"          // h = 0
        "s_waitcnt vmcnt(0)\n\t"
        CHUNK(0, "v116")
        CHUNK(1, "v117")
        CHUNK(2, "v118")
        CHUNK(3, "v119")
        CHUNK(4, "v120")
        CHUNK(5, "v121")
        CHUNK(6, "v122")
        CHUNK(7, "v123")
        "v_mov_b32 %[ho], v111\n\t"
        : [ho] "=v"(h)
        : [xlo] "v"(xlo), [xhi] "v"(xhi),
          [wlo] "v"(wlo), [whi] "v"(whi),
          [wih] "v"(w_ih_l), [bias] "v"(bias_l)
        : "memory", "scc", "s13", "s15",
          "s16","s17","s18","s19","s20","s21","s22","s23",
          "s24","s25","s26","s27","s28","s29","s30","s31",
          "s32","s33","s34","s35","s36","s37","s38","s39",
          "s40","s41","s42","s43","s44","s45","s46","s47",
          "s48","s49","s50","s51","s52","s53","s54","s55",
          "s56","s57","s58","s59","s60","s61","s62","s63",
          "s64","s65","s66","s67","s68","s69","s70","s71",
          "s72","s73","s74","s75","s76","s77","s78","s79",
          "v40","v41","v42","v43","v44","v45","v46","v47",
          "v48","v49","v50","v51","v52","v53","v54","v55",
          "v56","v57","v58","v59","v60","v61","v62","v63",
          "v64","v65","v66","v67","v68","v69","v70","v71",
          "v72","v73","v74","v75","v76","v77","v78","v79",
          "v80","v81","v82","v83","v84","v85","v86","v87",
          "v88","v89","v90","v91","v92","v93","v94","v95",
          "v96","v97","v98","v99","v100","v101","v102","v103",
          "v104","v105","v106","v107","v108","v109","v110","v111",
          "v112","v113","v114","v115","v116","v117","v118","v119",
          "v120","v121","v122","v123");

    // out[batch] = sum_i h[i]*fc_w[i] + fc_b  (wave butterfly reduce)
    float v = h * fc_w[lane];
#pragma unroll
    for (int off = 32; off > 0; off >>= 1)
        v += __shfl_xor(v, off, 64);

    if (lane == 0)
        out[batch] = v + fc_b[0];
}

extern "C" void kernel_launch(void* const* d_in, const int* in_sizes, int n_in,
                              void* d_out, int out_size, void* d_ws, size_t ws_size,
                              hipStream_t stream)
{
    const float* x    = (const float*)d_in[0];
    const float* W_ih = (const float*)d_in[1];
    const float* W_hh = (const float*)d_in[2];
    const float* b_ih = (const float*)d_in[3];
    const float* b_hh = (const float*)d_in[4];
    const float* fc_w = (const float*)d_in[5];
    const float* fc_b = (const float*)d_in[6];
    float* out = (float*)d_out;

    const int B = in_sizes[0] / TDIM;          // x is (B, T, 1)
    const int wavesPerBlock = 4;
    const int blocks = (B + wavesPerBlock - 1) / wavesPerBlock;

    rnn_asm_f32<<<blocks, wavesPerBlock * 64, 0, stream>>>(
        x, W_ih, W_hh, b_ih, b_hh, fc_w, fc_b, out, B);
}